// Round 3
// baseline (269.443 us; speedup 1.0000x reference)
//
#include <hip/hip_runtime.h>

#define D_IN  128
#define D_OUT 32
#define H     512
#define W     512
#define W4    128          // W/4 float4 lanes per row
#define HB    8            // output H rows per K2 block
#define ZR    (HB + 8)     // 16 rows incl. h-halo
#define K2THR 512

// ordered-uint encoding: monotone map float -> uint32 for atomicMin/Max
__device__ __forceinline__ unsigned f2key(float f) {
    unsigned u = __float_as_uint(f);
    return (u & 0x80000000u) ? ~u : (u | 0x80000000u);
}
__device__ __forceinline__ float key2f(unsigned k) {
    unsigned u = (k & 0x80000000u) ? (k ^ 0x80000000u) : ~k;
    return __uint_as_float(u);
}

// K1: depth conv, stride 4, pad 3. inp (128,512,512) -> bufA (32,512,512).
// Pure streaming, no LDS, 9 independent 16B loads per thread.
// Also initializes the global min/max atomic slots for K2.
__global__ void zconv_kernel(const float* __restrict__ inp, float* __restrict__ out,
                             const float* __restrict__ bz_p, unsigned* __restrict__ fin_u) {
    if (blockIdx.x == 0 && threadIdx.x == 0) {
        fin_u[0] = 0xFFFFFFFFu;  // running min key
        fin_u[1] = 0u;           // running max key
    }
    int tid = blockIdx.x * blockDim.x + threadIdx.x;
    int w4 = tid & (W4 - 1);
    int h  = (tid >> 7) & (H - 1);
    int d  = tid >> 16;
    float bz = bz_p[0];
    float iz = 1.0f / (2.0f * bz * bz);
    float wz[9];
#pragma unroll
    for (int k = 0; k < 9; ++k) {
        float dd = (float)(k - 4);
        wz[k] = expf(-dd * dd * iz);
    }
    const float4* in4 = (const float4*)inp;
    float4 acc = make_float4(0.f, 0.f, 0.f, 0.f);
    int base = h * W4 + w4;
#pragma unroll
    for (int k = 0; k < 9; ++k) {
        int din = 4 * d - 3 + k;
        if ((unsigned)din < D_IN) {                 // wave-uniform (d uniform per wave)
            float4 v = in4[din * (H * W4) + base];
            acc.x += v.x * wz[k]; acc.y += v.y * wz[k];
            acc.z += v.z * wz[k]; acc.w += v.w * wz[k];
        }
    }
    ((float4*)out)[d * (H * W4) + base] = acc;
}

// K2: h-conv + w-conv (both pad 4) on the (32,512,512) volume, fused min/max
// via ordered-uint atomics. LDS 48 KiB -> 3 blocks/CU.
__global__ __launch_bounds__(K2THR)
void hwconv_kernel(const float* __restrict__ in, float* __restrict__ out,
                   const float* __restrict__ bxy_p, unsigned* __restrict__ fin_u) {
    __shared__ float zbuf[ZR * W];   // 32 KiB
    __shared__ float hbuf[HB * W];   // 16 KiB
    __shared__ float smin[8], smax[8];

    const int d  = blockIdx.x >> 6;          // 64 h-tiles per slice
    const int h0 = (blockIdx.x & 63) * HB;

    float bx = bxy_p[0];
    float ix = 1.0f / (2.0f * bx * bx);
    float wx[9];
#pragma unroll
    for (int k = 0; k < 9; ++k) {
        float dd = (float)(k - 4);
        wx[k] = expf(-dd * dd * ix);
    }

    const float4* in4 = (const float4*)in;
    float4* z4 = (float4*)zbuf;
    float4* h4 = (float4*)hbuf;

    // Step A: stage tile rows [h0-4, h0+12) into LDS (streaming copy)
#pragma unroll
    for (int i = 0; i < (ZR * W4) / K2THR; ++i) {
        int t  = threadIdx.x + i * K2THR;
        int r  = t >> 7;
        int c4 = t & (W4 - 1);
        int h  = h0 - 4 + r;
        z4[t] = ((unsigned)h < H) ? in4[(d * H + h) * W4 + c4]
                                  : make_float4(0.f, 0.f, 0.f, 0.f);
    }
    __syncthreads();

    // Step B: h-conv zbuf -> hbuf
#pragma unroll
    for (int i = 0; i < (HB * W4) / K2THR; ++i) {
        int t  = threadIdx.x + i * K2THR;
        int r  = t >> 7;
        int c4 = t & (W4 - 1);
        float4 acc = make_float4(0.f, 0.f, 0.f, 0.f);
#pragma unroll
        for (int k = 0; k < 9; ++k) {
            float4 v = z4[(r + k) * W4 + c4];
            acc.x += v.x * wx[k]; acc.y += v.y * wx[k];
            acc.z += v.z * wx[k]; acc.w += v.w * wx[k];
        }
        h4[t] = acc;
    }
    __syncthreads();

    // Step C: w-conv hbuf -> global, local min/max
    float lmin =  3.402823466e38f;
    float lmax = -3.402823466e38f;
    float4* out4 = (float4*)out;
#pragma unroll
    for (int i = 0; i < (HB * W4) / K2THR; ++i) {
        int t  = threadIdx.x + i * K2THR;
        int r  = t >> 7;
        int c4 = t & (W4 - 1);
        float4 zv = make_float4(0.f, 0.f, 0.f, 0.f);
        float4 va = (c4 > 0)      ? h4[r * W4 + c4 - 1] : zv;
        float4 vb =                 h4[r * W4 + c4];
        float4 vc = (c4 < W4 - 1) ? h4[r * W4 + c4 + 1] : zv;
        float win[12] = {va.x, va.y, va.z, va.w,
                         vb.x, vb.y, vb.z, vb.w,
                         vc.x, vc.y, vc.z, vc.w};
        float4 o = make_float4(0.f, 0.f, 0.f, 0.f);
#pragma unroll
        for (int k = 0; k < 9; ++k) {
            o.x += win[k]     * wx[k];
            o.y += win[k + 1] * wx[k];
            o.z += win[k + 2] * wx[k];
            o.w += win[k + 3] * wx[k];
        }
        out4[(d * H + h0 + r) * W4 + c4] = o;
        lmin = fminf(lmin, fminf(fminf(o.x, o.y), fminf(o.z, o.w)));
        lmax = fmaxf(lmax, fmaxf(fmaxf(o.x, o.y), fmaxf(o.z, o.w)));
    }

    // block reduce -> 2 atomics (order-independent => deterministic)
#pragma unroll
    for (int off = 32; off > 0; off >>= 1) {
        lmin = fminf(lmin, __shfl_down(lmin, off, 64));
        lmax = fmaxf(lmax, __shfl_down(lmax, off, 64));
    }
    int lane = threadIdx.x & 63, wv = threadIdx.x >> 6;
    if (lane == 0) { smin[wv] = lmin; smax[wv] = lmax; }
    __syncthreads();
    if (threadIdx.x == 0) {
        float mn = smin[0], mx = smax[0];
#pragma unroll
        for (int i = 1; i < 8; ++i) { mn = fminf(mn, smin[i]); mx = fmaxf(mx, smax[i]); }
        atomicMin(&fin_u[0], f2key(mn));
        atomicMax(&fin_u[1], f2key(mx));
    }
}

// K3: normalize.
__global__ void norm_kernel(const float* __restrict__ in, float* __restrict__ out,
                            const unsigned* __restrict__ fin_u) {
    int tid = blockIdx.x * blockDim.x + threadIdx.x;
    float mn  = key2f(fin_u[0]);
    float mx  = key2f(fin_u[1]);
    float inv = 1.0f / (mx - mn);
    float4 v = ((const float4*)in)[tid];
    ((float4*)out)[tid] = make_float4((v.x - mn) * inv, (v.y - mn) * inv,
                                      (v.z - mn) * inv, (v.w - mn) * inv);
}

extern "C" void kernel_launch(void* const* d_in, const int* in_sizes, int n_in,
                              void* d_out, int out_size, void* d_ws, size_t ws_size,
                              hipStream_t stream) {
    const float* inp    = (const float*)d_in[0];
    // mu_z / sig_z produce a positive global scale that cancels in min-max norm.
    const float* bet_xy = (const float*)d_in[3];
    const float* bet_z  = (const float*)d_in[4];
    float* out = (float*)d_out;

    char* ws = (char*)d_ws;
    unsigned* fin_u = (unsigned*)ws;             // 2 encoded uints
    float* bufA = (float*)(ws + 65536);          // 32 MiB z-conv output
    float* bufB = (float*)(ws + 65536 + (size_t)33554432);  // 32 MiB hw-conv output

    const int NTASK = D_OUT * H * W4;            // 2,097,152 float4
    // K1: z-conv (stream 128 MiB -> 32 MiB), init min/max slots
    zconv_kernel<<<NTASK / 256, 256, 0, stream>>>(inp, bufA, bet_z, fin_u);
    // K2: h+w conv + fused min/max atomics
    hwconv_kernel<<<D_OUT * (H / HB), K2THR, 0, stream>>>(bufA, bufB, bet_xy, fin_u);
    // K3: normalize
    norm_kernel<<<NTASK / 256, 256, 0, stream>>>(bufB, out, fin_u);
}